// Round 2
// baseline (1261.319 us; speedup 1.0000x reference)
//
#include <hip/hip_runtime.h>

#define D_DIM 4096   // out_f = in_f
#define M_DIM 8192   // B*S = 4*2048
#define NB_   512    // n_blocks = 4096/8
#define KC_   2048   // compacted K = 4 per block * 512

typedef __attribute__((ext_vector_type(8))) short s8v;
typedef __attribute__((ext_vector_type(4))) float f4v;

static __device__ __forceinline__ unsigned short f2bf(float f) {
  union { float f; unsigned u; } c; c.f = f;
  unsigned r = c.u + 0x7fffu + ((c.u >> 16) & 1u);  // RNE
  return (unsigned short)(r >> 16);
}

// select element i (0..7) from two float4s without runtime-indexed array (rule #20)
static __device__ __forceinline__ float pick8(float4 a, float4 b, int i) {
  float lo = (i & 1) ? ((i & 2) ? a.w : a.y) : ((i & 2) ? a.z : a.x);
  float hi = (i & 1) ? ((i & 2) ? b.w : b.y) : ((i & 2) ? b.z : b.x);
  return (i & 4) ? hi : lo;
}

// ---- Kernel A1: col_imp[c] = sum_r |W[r][c]| ------------------------------
__global__ void colsum_kernel(const float* __restrict__ W, float* __restrict__ col_imp) {
  int col = blockIdx.x * 256 + threadIdx.x;  // 16 x-blocks * 256 = 4096 cols
  int r0 = blockIdx.y * 128;                 // 32 y-blocks * 128 = 4096 rows
  float s = 0.f;
  #pragma unroll 4
  for (int r = r0; r < r0 + 128; ++r)
    s += fabsf(W[(size_t)r * D_DIM + col]);
  atomicAdd(&col_imp[col], s);
}

// ---- Kernel A2: per 8-block, top-4 indices (desc value, asc index ties) ---
__global__ void top4_kernel(const float* __restrict__ col_imp, int4* __restrict__ top_idx) {
  int blk = blockIdx.x * 256 + threadIdx.x;
  if (blk >= NB_) return;
  float4 a = *(const float4*)&col_imp[blk * 8];
  float4 b = *(const float4*)&col_imp[blk * 8 + 4];
  float v[8] = {a.x, a.y, a.z, a.w, b.x, b.y, b.z, b.w};
  int used = 0;
  int sel[4];
  #pragma unroll
  for (int j = 0; j < 4; ++j) {
    float best = -1.f;
    int bi = 0;
    #pragma unroll
    for (int c = 0; c < 8; ++c) {
      bool ok = (((used >> c) & 1) == 0) && (v[c] > best);  // strict > : lowest idx on tie
      best = ok ? v[c] : best;
      bi = ok ? c : bi;
    }
    used |= (1 << bi);
    sel[j] = bi;
  }
  top_idx[blk] = make_int4(sel[0], sel[1], sel[2], sel[3]);
}

// ---- Kernel B: soft-threshold, write compact Wc (bf16, unscaled), num/den -
__global__ void soft_kernel(const float* __restrict__ W, const int4* __restrict__ top_idx,
                            unsigned short* __restrict__ Wc, float* __restrict__ accum) {
  int gtid = blockIdx.x * 256 + threadIdx.x;  // 4096*512 = 2M threads
  int row = gtid >> 9, blk = gtid & 511;
  const float* base = W + (size_t)row * D_DIM + blk * 8;
  float4 a = *(const float4*)base;
  float4 b = *(const float4*)(base + 4);
  int4 idx = top_idx[blk];
  float r0 = pick8(a, b, idx.x), r1 = pick8(a, b, idx.y);
  float r2 = pick8(a, b, idx.z), r3 = pick8(a, b, idx.w);
  float a0 = fabsf(r0), a1 = fabsf(r1), a2 = fabsf(r2), a3 = fabsf(r3);
  // second-smallest of 4
  float lo1 = fminf(a0, a1), hi1 = fmaxf(a0, a1);
  float lo2 = fminf(a2, a3), hi2 = fmaxf(a2, a3);
  float thr = fminf(fmaxf(lo1, lo2), fminf(hi1, hi2));
  float s0 = copysignf(fmaxf(a0 - thr, 0.f), r0);
  float s1 = copysignf(fmaxf(a1 - thr, 0.f), r1);
  float s2 = copysignf(fmaxf(a2 - thr, 0.f), r2);
  float s3 = copysignf(fmaxf(a3 - thr, 0.f), r3);
  *(ushort4*)&Wc[(size_t)row * KC_ + blk * 4] =
      make_ushort4(f2bf(s0), f2bf(s1), f2bf(s2), f2bf(s3));
  float nm = r0 * s0 + r1 * s1 + r2 * s2 + r3 * s3;
  float dn = s0 * s0 + s1 * s1 + s2 * s2 + s3 * s3;
  #pragma unroll
  for (int off = 32; off > 0; off >>= 1) {
    nm += __shfl_down(nm, off);
    dn += __shfl_down(dn, off);
  }
  if ((threadIdx.x & 63) == 0) {
    atomicAdd(&accum[0], nm);
    atomicAdd(&accum[1], dn);
  }
}

// ---- Kernel X: compact x -> bf16, gather 4-of-8 per block -----------------
__global__ void xcompact_kernel(const float* __restrict__ x, const int4* __restrict__ top_idx,
                                unsigned short* __restrict__ xc) {
  int gtid = blockIdx.x * 256 + threadIdx.x;  // 8192*512 = 4M threads
  int row = gtid >> 9, blk = gtid & 511;
  const float* base = x + (size_t)row * D_DIM + blk * 8;
  float4 a = *(const float4*)base;
  float4 b = *(const float4*)(base + 4);
  int4 idx = top_idx[blk];
  *(ushort4*)&xc[(size_t)row * KC_ + blk * 4] =
      make_ushort4(f2bf(pick8(a, b, idx.x)), f2bf(pick8(a, b, idx.y)),
                   f2bf(pick8(a, b, idx.z)), f2bf(pick8(a, b, idx.w)));
}

// ---- GEMM: C[m][n] = beta * sum_k A[m][k]*Bw[n][k], bf16 MFMA -------------
#define BM 128
#define BN 128
#define BK 32

__global__ __launch_bounds__(256) void gemm_kernel(const unsigned short* __restrict__ A,
                                                   const unsigned short* __restrict__ Bw,
                                                   const float* __restrict__ accum,
                                                   float* __restrict__ C) {
  __shared__ __align__(16) unsigned short As[BM * BK];  // 8 KB
  __shared__ __align__(16) unsigned short Bs[BN * BK];  // 8 KB
  const int tid = threadIdx.x;
  const int lane = tid & 63;
  const int m0 = blockIdx.y * BM;
  const int n0 = blockIdx.x * BN;
  const int wid = tid >> 6;
  const int wm = (wid >> 1) * 64;  // wave row offset in tile
  const int wn = (wid & 1) * 64;   // wave col offset in tile

  f4v acc[4][4];
  const f4v zf = {0.f, 0.f, 0.f, 0.f};
  #pragma unroll
  for (int i = 0; i < 4; ++i)
    #pragma unroll
    for (int j = 0; j < 4; ++j)
      acc[i][j] = zf;

  // staging: 256 threads * 16B = 4KB = 64 rows x 64B; two calls per operand
  const int rA = tid >> 2;         // row 0..63 within half-tile
  const int cA = (tid & 3) * 8;    // k element offset (0,8,16,24)
  const unsigned short* gA = A + (size_t)(m0 + rA) * KC_ + cA;
  const unsigned short* gB = Bw + (size_t)(n0 + rA) * KC_ + cA;

  const int fr = lane & 15;        // fragment row
  const int fc = (lane >> 4) * 8;  // fragment k-chunk

  for (int k0 = 0; k0 < KC_; k0 += BK) {
    __builtin_amdgcn_global_load_lds(
        (const __attribute__((address_space(1))) void*)(gA + k0),
        (__attribute__((address_space(3))) void*)(As + tid * 8), 16, 0, 0);
    __builtin_amdgcn_global_load_lds(
        (const __attribute__((address_space(1))) void*)(gA + (size_t)64 * KC_ + k0),
        (__attribute__((address_space(3))) void*)(As + 2048 + tid * 8), 16, 0, 0);
    __builtin_amdgcn_global_load_lds(
        (const __attribute__((address_space(1))) void*)(gB + k0),
        (__attribute__((address_space(3))) void*)(Bs + tid * 8), 16, 0, 0);
    __builtin_amdgcn_global_load_lds(
        (const __attribute__((address_space(1))) void*)(gB + (size_t)64 * KC_ + k0),
        (__attribute__((address_space(3))) void*)(Bs + 2048 + tid * 8), 16, 0, 0);
    __syncthreads();

    s8v af[4], bf[4];
    #pragma unroll
    for (int i = 0; i < 4; ++i)
      af[i] = *(const s8v*)&As[(wm + i * 16 + fr) * BK + fc];
    #pragma unroll
    for (int i = 0; i < 4; ++i)
      bf[i] = *(const s8v*)&Bs[(wn + i * 16 + fr) * BK + fc];
    #pragma unroll
    for (int i = 0; i < 4; ++i)
      #pragma unroll
      for (int j = 0; j < 4; ++j)
        acc[i][j] = __builtin_amdgcn_mfma_f32_16x16x32_bf16(af[i], bf[j], acc[i][j], 0, 0, 0);
    __syncthreads();
  }

  float nm = accum[0], dn = accum[1];
  float beta = (dn > 0.f) ? (nm / dn) : 1.f;

  // C/D layout: col = lane&15, row = (lane>>4)*4 + reg  [m89/m91 verified]
  const int col = lane & 15;
  const int rb = (lane >> 4) * 4;
  #pragma unroll
  for (int i = 0; i < 4; ++i)
    #pragma unroll
    for (int j = 0; j < 4; ++j)
      #pragma unroll
      for (int v = 0; v < 4; ++v)
        C[(size_t)(m0 + wm + i * 16 + rb + v) * D_DIM + (n0 + wn + j * 16 + col)] =
            beta * acc[i][j][v];
}

extern "C" void kernel_launch(void* const* d_in, const int* in_sizes, int n_in,
                              void* d_out, int out_size, void* d_ws, size_t ws_size,
                              hipStream_t stream) {
  const float* x = (const float*)d_in[0];
  const float* W = (const float*)d_in[1];
  float* out = (float*)d_out;
  char* ws = (char*)d_ws;

  // ws layout: [top_idx 8KB][col_imp 16KB][accum 8B pad to 8KB][xc 32MB][wc 16MB]
  int4* top_idx = (int4*)ws;
  float* col_imp = (float*)(ws + 8192);
  float* accum = (float*)(ws + 8192 + 16384);
  unsigned short* xc = (unsigned short*)(ws + 32768);
  unsigned short* wc = (unsigned short*)(ws + 32768 + (size_t)M_DIM * KC_ * 2);

  // zero col_imp + accum (ws is poisoned 0xAA before each call)
  hipMemsetAsync(ws + 8192, 0, 16384 + 8, stream);

  colsum_kernel<<<dim3(16, 32), 256, 0, stream>>>(W, col_imp);
  top4_kernel<<<2, 256, 0, stream>>>(col_imp, top_idx);
  soft_kernel<<<8192, 256, 0, stream>>>(W, top_idx, wc, accum);
  xcompact_kernel<<<16384, 256, 0, stream>>>(x, top_idx, xc);
  gemm_kernel<<<dim3(D_DIM / BN, M_DIM / BM), 256, 0, stream>>>(xc, wc, accum, out);
}

// Round 3
// 448.512 us; speedup vs baseline: 2.8122x; 2.8122x over previous
//
#include <hip/hip_runtime.h>

#define D_DIM 4096   // out_f = in_f
#define M_DIM 8192   // B*S = 4*2048
#define NB_   512    // n_blocks = 4096/8
#define KC_   2048   // compacted K = 4 per block * 512

typedef __attribute__((ext_vector_type(8))) short s8v;
typedef __attribute__((ext_vector_type(4))) float f4v;

static __device__ __forceinline__ unsigned short f2bf(float f) {
  union { float f; unsigned u; } c; c.f = f;
  unsigned r = c.u + 0x7fffu + ((c.u >> 16) & 1u);  // RNE
  return (unsigned short)(r >> 16);
}

// select element i (0..7) from two float4s without runtime-indexed array (rule #20)
static __device__ __forceinline__ float pick8(float4 a, float4 b, int i) {
  float lo = (i & 1) ? ((i & 2) ? a.w : a.y) : ((i & 2) ? a.z : a.x);
  float hi = (i & 1) ? ((i & 2) ? b.w : b.y) : ((i & 2) ? b.z : b.x);
  return (i & 4) ? hi : lo;
}

// ---- Kernel A1: col_imp[c] = sum_r |W[r][c]| ------------------------------
__global__ void colsum_kernel(const float* __restrict__ W, float* __restrict__ col_imp) {
  int col = blockIdx.x * 256 + threadIdx.x;  // 16 x-blocks * 256 = 4096 cols
  int r0 = blockIdx.y * 128;                 // 32 y-blocks * 128 = 4096 rows
  float s = 0.f;
  #pragma unroll 4
  for (int r = r0; r < r0 + 128; ++r)
    s += fabsf(W[(size_t)r * D_DIM + col]);
  atomicAdd(&col_imp[col], s);  // 4096 distinct addresses x 32 adds: no hot-spot
}

// ---- Kernel A2: per 8-block, top-4 indices (desc value, asc index ties) ---
__global__ void top4_kernel(const float* __restrict__ col_imp, int4* __restrict__ top_idx) {
  int blk = blockIdx.x * 256 + threadIdx.x;
  if (blk >= NB_) return;
  float4 a = *(const float4*)&col_imp[blk * 8];
  float4 b = *(const float4*)&col_imp[blk * 8 + 4];
  float v[8] = {a.x, a.y, a.z, a.w, b.x, b.y, b.z, b.w};
  int used = 0;
  int sel[4];
  #pragma unroll
  for (int j = 0; j < 4; ++j) {
    float best = -1.f;
    int bi = 0;
    #pragma unroll
    for (int c = 0; c < 8; ++c) {
      bool ok = (((used >> c) & 1) == 0) && (v[c] > best);  // strict > : lowest idx on tie
      best = ok ? v[c] : best;
      bi = ok ? c : bi;
    }
    used |= (1 << bi);
    sel[j] = bi;
  }
  top_idx[blk] = make_int4(sel[0], sel[1], sel[2], sel[3]);
}

// ---- Kernel B: soft-threshold, write compact Wc (bf16), per-block partial -
// 2048 blocks x 1024 threads; NO same-address atomics (was 836us of atomic
// serialization on accum[0/1] — round-2 post-mortem).
__global__ __launch_bounds__(1024) void soft_kernel(const float* __restrict__ W,
                                                    const int4* __restrict__ top_idx,
                                                    unsigned short* __restrict__ Wc,
                                                    float2* __restrict__ partials) {
  __shared__ float rn[16], rd[16];
  int gtid = blockIdx.x * 1024 + threadIdx.x;  // 2M threads = 4096 rows * 512 blks
  int row = gtid >> 9, blk = gtid & 511;
  const float* base = W + (size_t)row * D_DIM + blk * 8;
  float4 a = *(const float4*)base;
  float4 b = *(const float4*)(base + 4);
  int4 idx = top_idx[blk];
  float r0 = pick8(a, b, idx.x), r1 = pick8(a, b, idx.y);
  float r2 = pick8(a, b, idx.z), r3 = pick8(a, b, idx.w);
  float a0 = fabsf(r0), a1 = fabsf(r1), a2 = fabsf(r2), a3 = fabsf(r3);
  // second-smallest of 4
  float lo1 = fminf(a0, a1), hi1 = fmaxf(a0, a1);
  float lo2 = fminf(a2, a3), hi2 = fmaxf(a2, a3);
  float thr = fminf(fmaxf(lo1, lo2), fminf(hi1, hi2));
  float s0 = copysignf(fmaxf(a0 - thr, 0.f), r0);
  float s1 = copysignf(fmaxf(a1 - thr, 0.f), r1);
  float s2 = copysignf(fmaxf(a2 - thr, 0.f), r2);
  float s3 = copysignf(fmaxf(a3 - thr, 0.f), r3);
  *(ushort4*)&Wc[(size_t)row * KC_ + blk * 4] =
      make_ushort4(f2bf(s0), f2bf(s1), f2bf(s2), f2bf(s3));
  float nm = r0 * s0 + r1 * s1 + r2 * s2 + r3 * s3;
  float dn = s0 * s0 + s1 * s1 + s2 * s2 + s3 * s3;
  #pragma unroll
  for (int off = 32; off > 0; off >>= 1) {
    nm += __shfl_down(nm, off);
    dn += __shfl_down(dn, off);
  }
  int wv = threadIdx.x >> 6;
  if ((threadIdx.x & 63) == 0) { rn[wv] = nm; rd[wv] = dn; }
  __syncthreads();
  if (threadIdx.x == 0) {
    float n = 0.f, d = 0.f;
    #pragma unroll
    for (int i = 0; i < 16; ++i) { n += rn[i]; d += rd[i]; }
    partials[blockIdx.x] = make_float2(n, d);
  }
}

// ---- Kernel B2: reduce 2048 partials -> beta ------------------------------
__global__ __launch_bounds__(256) void beta_kernel(const float2* __restrict__ partials,
                                                   float* __restrict__ beta_out) {
  __shared__ float rn[4], rd[4];
  float nm = 0.f, dn = 0.f;
  for (int i = threadIdx.x; i < 2048; i += 256) {
    float2 p = partials[i];
    nm += p.x;
    dn += p.y;
  }
  #pragma unroll
  for (int off = 32; off > 0; off >>= 1) {
    nm += __shfl_down(nm, off);
    dn += __shfl_down(dn, off);
  }
  int wv = threadIdx.x >> 6;
  if ((threadIdx.x & 63) == 0) { rn[wv] = nm; rd[wv] = dn; }
  __syncthreads();
  if (threadIdx.x == 0) {
    float n = rn[0] + rn[1] + rn[2] + rn[3];
    float d = rd[0] + rd[1] + rd[2] + rd[3];
    beta_out[0] = (d > 0.f) ? (n / d) : 1.f;
  }
}

// ---- Kernel X: compact x -> bf16, gather 4-of-8 per block -----------------
__global__ void xcompact_kernel(const float* __restrict__ x, const int4* __restrict__ top_idx,
                                unsigned short* __restrict__ xc) {
  int gtid = blockIdx.x * 256 + threadIdx.x;  // 8192*512 = 4M threads
  int row = gtid >> 9, blk = gtid & 511;
  const float* base = x + (size_t)row * D_DIM + blk * 8;
  float4 a = *(const float4*)base;
  float4 b = *(const float4*)(base + 4);
  int4 idx = top_idx[blk];
  *(ushort4*)&xc[(size_t)row * KC_ + blk * 4] =
      make_ushort4(f2bf(pick8(a, b, idx.x)), f2bf(pick8(a, b, idx.y)),
                   f2bf(pick8(a, b, idx.z)), f2bf(pick8(a, b, idx.w)));
}

// ---- GEMM: C[m][n] = beta * sum_k A[m][k]*Bw[n][k], bf16 MFMA -------------
#define BM 128
#define BN 128
#define BK 32

__global__ __launch_bounds__(256) void gemm_kernel(const unsigned short* __restrict__ A,
                                                   const unsigned short* __restrict__ Bw,
                                                   const float* __restrict__ beta_p,
                                                   float* __restrict__ C) {
  __shared__ __align__(16) unsigned short As[BM * BK];  // 8 KB
  __shared__ __align__(16) unsigned short Bs[BN * BK];  // 8 KB
  const int tid = threadIdx.x;
  const int lane = tid & 63;

  // bijective XCD-aware swizzle (nwg=2048, 2048%8==0) [m157/m192: +10% when
  // L2-panel reuse matters]
  const int nwg = gridDim.x;            // 2048
  const int orig = blockIdx.x;
  const int wgid = (orig & 7) * (nwg >> 3) + (orig >> 3);
  const int m0 = (wgid >> 5) * BM;      // 64 m-tiles
  const int n0 = (wgid & 31) * BN;      // 32 n-tiles

  const int wid = tid >> 6;
  const int wm = (wid >> 1) * 64;  // wave row offset in tile
  const int wn = (wid & 1) * 64;   // wave col offset in tile

  f4v acc[4][4];
  const f4v zf = {0.f, 0.f, 0.f, 0.f};
  #pragma unroll
  for (int i = 0; i < 4; ++i)
    #pragma unroll
    for (int j = 0; j < 4; ++j)
      acc[i][j] = zf;

  // staging: 256 threads * 16B = 4KB = 64 rows x 64B; two calls per operand
  const int rA = tid >> 2;         // row 0..63 within half-tile
  const int cA = (tid & 3) * 8;    // k element offset (0,8,16,24)
  const unsigned short* gA = A + (size_t)(m0 + rA) * KC_ + cA;
  const unsigned short* gB = Bw + (size_t)(n0 + rA) * KC_ + cA;

  const int fr = lane & 15;        // fragment row
  const int fc = (lane >> 4) * 8;  // fragment k-chunk

  for (int k0 = 0; k0 < KC_; k0 += BK) {
    __builtin_amdgcn_global_load_lds(
        (const __attribute__((address_space(1))) void*)(gA + k0),
        (__attribute__((address_space(3))) void*)(As + tid * 8), 16, 0, 0);
    __builtin_amdgcn_global_load_lds(
        (const __attribute__((address_space(1))) void*)(gA + (size_t)64 * KC_ + k0),
        (__attribute__((address_space(3))) void*)(As + 2048 + tid * 8), 16, 0, 0);
    __builtin_amdgcn_global_load_lds(
        (const __attribute__((address_space(1))) void*)(gB + k0),
        (__attribute__((address_space(3))) void*)(Bs + tid * 8), 16, 0, 0);
    __builtin_amdgcn_global_load_lds(
        (const __attribute__((address_space(1))) void*)(gB + (size_t)64 * KC_ + k0),
        (__attribute__((address_space(3))) void*)(Bs + 2048 + tid * 8), 16, 0, 0);
    __syncthreads();

    s8v af[4], bf[4];
    #pragma unroll
    for (int i = 0; i < 4; ++i)
      af[i] = *(const s8v*)&As[(wm + i * 16 + fr) * BK + fc];
    #pragma unroll
    for (int i = 0; i < 4; ++i)
      bf[i] = *(const s8v*)&Bs[(wn + i * 16 + fr) * BK + fc];
    #pragma unroll
    for (int i = 0; i < 4; ++i)
      #pragma unroll
      for (int j = 0; j < 4; ++j)
        acc[i][j] = __builtin_amdgcn_mfma_f32_16x16x32_bf16(af[i], bf[j], acc[i][j], 0, 0, 0);
    __syncthreads();
  }

  const float beta = beta_p[0];

  // C/D layout: col = lane&15, row = (lane>>4)*4 + reg  [m89/m91 verified]
  const int col = lane & 15;
  const int rb = (lane >> 4) * 4;
  #pragma unroll
  for (int i = 0; i < 4; ++i)
    #pragma unroll
    for (int j = 0; j < 4; ++j)
      #pragma unroll
      for (int v = 0; v < 4; ++v)
        C[(size_t)(m0 + wm + i * 16 + rb + v) * D_DIM + (n0 + wn + j * 16 + col)] =
            beta * acc[i][j][v];
}

extern "C" void kernel_launch(void* const* d_in, const int* in_sizes, int n_in,
                              void* d_out, int out_size, void* d_ws, size_t ws_size,
                              hipStream_t stream) {
  const float* x = (const float*)d_in[0];
  const float* W = (const float*)d_in[1];
  float* out = (float*)d_out;
  char* ws = (char*)d_ws;

  // ws layout: [top_idx 8KB][col_imp 16KB -- reused as partials after top4]
  //            [beta 8KB pad][xc 32MB][wc 16MB]
  int4* top_idx = (int4*)ws;
  float* col_imp = (float*)(ws + 8192);
  float2* partials = (float2*)(ws + 8192);  // aliases col_imp (dead after top4)
  float* beta_buf = (float*)(ws + 8192 + 16384);
  unsigned short* xc = (unsigned short*)(ws + 32768);
  unsigned short* wc = (unsigned short*)(ws + 32768 + (size_t)M_DIM * KC_ * 2);

  // zero col_imp (ws is poisoned 0xAA before each call); partials/beta are
  // fully written before being read — no zeroing needed
  hipMemsetAsync(ws + 8192, 0, 16384, stream);

  colsum_kernel<<<dim3(16, 32), 256, 0, stream>>>(W, col_imp);
  top4_kernel<<<2, 256, 0, stream>>>(col_imp, top_idx);
  soft_kernel<<<2048, 1024, 0, stream>>>(W, top_idx, wc, partials);
  beta_kernel<<<1, 256, 0, stream>>>(partials, beta_buf);
  xcompact_kernel<<<16384, 256, 0, stream>>>(x, top_idx, xc);
  gemm_kernel<<<2048, 256, 0, stream>>>(xc, wc, beta_buf, out);
}

// Round 5
// 417.189 us; speedup vs baseline: 3.0234x; 1.0751x over previous
//
#include <hip/hip_runtime.h>

#define D_DIM 4096   // out_f = in_f
#define M_DIM 8192   // B*S = 4*2048
#define NB_   512    // n_blocks = 4096/8
#define KC_   2048   // compacted K = 4 per block * 512
#define NKT   (KC_ / 64)  // 32 K-tiles of 64

typedef __attribute__((ext_vector_type(8))) short s8v;
typedef __attribute__((ext_vector_type(4))) float f4v;

static __device__ __forceinline__ unsigned short f2bf(float f) {
  union { float f; unsigned u; } c; c.f = f;
  unsigned r = c.u + 0x7fffu + ((c.u >> 16) & 1u);  // RNE
  return (unsigned short)(r >> 16);
}

// select element i (0..7) from two float4s without runtime-indexed array (rule #20)
static __device__ __forceinline__ float pick8(float4 a, float4 b, int i) {
  float lo = (i & 1) ? ((i & 2) ? a.w : a.y) : ((i & 2) ? a.z : a.x);
  float hi = (i & 1) ? ((i & 2) ? b.w : b.y) : ((i & 2) ? b.z : b.x);
  return (i & 4) ? hi : lo;
}

// ---- Kernel A1: col_imp[c] = sum_r |W[r][c]| ------------------------------
__global__ void colsum_kernel(const float* __restrict__ W, float* __restrict__ col_imp) {
  int col = blockIdx.x * 256 + threadIdx.x;
  int r0 = blockIdx.y * 128;
  float s = 0.f;
  #pragma unroll 4
  for (int r = r0; r < r0 + 128; ++r)
    s += fabsf(W[(size_t)r * D_DIM + col]);
  atomicAdd(&col_imp[col], s);  // 4096 distinct addresses: no hot-spot
}

// ---- Kernel A2: per 8-block, top-4 indices (desc value, asc index ties) ---
__global__ void top4_kernel(const float* __restrict__ col_imp, int4* __restrict__ top_idx) {
  int blk = blockIdx.x * 256 + threadIdx.x;
  if (blk >= NB_) return;
  float4 a = *(const float4*)&col_imp[blk * 8];
  float4 b = *(const float4*)&col_imp[blk * 8 + 4];
  float v[8] = {a.x, a.y, a.z, a.w, b.x, b.y, b.z, b.w};
  int used = 0;
  int sel[4];
  #pragma unroll
  for (int j = 0; j < 4; ++j) {
    float best = -1.f;
    int bi = 0;
    #pragma unroll
    for (int c = 0; c < 8; ++c) {
      bool ok = (((used >> c) & 1) == 0) && (v[c] > best);
      best = ok ? v[c] : best;
      bi = ok ? c : bi;
    }
    used |= (1 << bi);
    sel[j] = bi;
  }
  top_idx[blk] = make_int4(sel[0], sel[1], sel[2], sel[3]);
}

// ---- Kernel B: soft-threshold, write compact Wc (bf16), per-block partial -
__global__ __launch_bounds__(1024) void soft_kernel(const float* __restrict__ W,
                                                    const int4* __restrict__ top_idx,
                                                    unsigned short* __restrict__ Wc,
                                                    float2* __restrict__ partials) {
  __shared__ float rn[16], rd[16];
  int gtid = blockIdx.x * 1024 + threadIdx.x;
  int row = gtid >> 9, blk = gtid & 511;
  const float* base = W + (size_t)row * D_DIM + blk * 8;
  float4 a = *(const float4*)base;
  float4 b = *(const float4*)(base + 4);
  int4 idx = top_idx[blk];
  float r0 = pick8(a, b, idx.x), r1 = pick8(a, b, idx.y);
  float r2 = pick8(a, b, idx.z), r3 = pick8(a, b, idx.w);
  float a0 = fabsf(r0), a1 = fabsf(r1), a2 = fabsf(r2), a3 = fabsf(r3);
  float lo1 = fminf(a0, a1), hi1 = fmaxf(a0, a1);
  float lo2 = fminf(a2, a3), hi2 = fmaxf(a2, a3);
  float thr = fminf(fmaxf(lo1, lo2), fminf(hi1, hi2));  // 2nd-smallest of 4
  float s0 = copysignf(fmaxf(a0 - thr, 0.f), r0);
  float s1 = copysignf(fmaxf(a1 - thr, 0.f), r1);
  float s2 = copysignf(fmaxf(a2 - thr, 0.f), r2);
  float s3 = copysignf(fmaxf(a3 - thr, 0.f), r3);
  *(ushort4*)&Wc[(size_t)row * KC_ + blk * 4] =
      make_ushort4(f2bf(s0), f2bf(s1), f2bf(s2), f2bf(s3));
  float nm = r0 * s0 + r1 * s1 + r2 * s2 + r3 * s3;
  float dn = s0 * s0 + s1 * s1 + s2 * s2 + s3 * s3;
  #pragma unroll
  for (int off = 32; off > 0; off >>= 1) {
    nm += __shfl_down(nm, off);
    dn += __shfl_down(dn, off);
  }
  int wv = threadIdx.x >> 6;
  if ((threadIdx.x & 63) == 0) { rn[wv] = nm; rd[wv] = dn; }
  __syncthreads();
  if (threadIdx.x == 0) {
    float n = 0.f, d = 0.f;
    #pragma unroll
    for (int i = 0; i < 16; ++i) { n += rn[i]; d += rd[i]; }
    partials[blockIdx.x] = make_float2(n, d);
  }
}

// ---- Kernel B2: reduce 2048 partials -> beta ------------------------------
__global__ __launch_bounds__(256) void beta_kernel(const float2* __restrict__ partials,
                                                   float* __restrict__ beta_out) {
  __shared__ float rn[4], rd[4];
  float nm = 0.f, dn = 0.f;
  for (int i = threadIdx.x; i < 2048; i += 256) {
    float2 p = partials[i];
    nm += p.x;
    dn += p.y;
  }
  #pragma unroll
  for (int off = 32; off > 0; off >>= 1) {
    nm += __shfl_down(nm, off);
    dn += __shfl_down(dn, off);
  }
  int wv = threadIdx.x >> 6;
  if ((threadIdx.x & 63) == 0) { rn[wv] = nm; rd[wv] = dn; }
  __syncthreads();
  if (threadIdx.x == 0) {
    float n = rn[0] + rn[1] + rn[2] + rn[3];
    float d = rd[0] + rd[1] + rd[2] + rd[3];
    beta_out[0] = (d > 0.f) ? (n / d) : 1.f;
  }
}

// ---- Kernel X: compact x -> bf16, gather 4-of-8 per block -----------------
__global__ void xcompact_kernel(const float* __restrict__ x, const int4* __restrict__ top_idx,
                                unsigned short* __restrict__ xc) {
  int gtid = blockIdx.x * 256 + threadIdx.x;
  int row = gtid >> 9, blk = gtid & 511;
  const float* base = x + (size_t)row * D_DIM + blk * 8;
  float4 a = *(const float4*)base;
  float4 b = *(const float4*)(base + 4);
  int4 idx = top_idx[blk];
  *(ushort4*)&xc[(size_t)row * KC_ + blk * 4] =
      make_ushort4(f2bf(pick8(a, b, idx.x)), f2bf(pick8(a, b, idx.y)),
                   f2bf(pick8(a, b, idx.z)), f2bf(pick8(a, b, idx.w)));
}

// ---- GEMM: 256x256 tile, BK=64, 8-phase counted-vmcnt pipeline (T2+T3+T4+T5)
// C[m][n] = beta * sum_k A[m][k]*Bw[n][k]
#define GLDS16(g, l)                                                          \
  __builtin_amdgcn_global_load_lds(                                           \
      (const __attribute__((address_space(1))) void*)(g),                     \
      (__attribute__((address_space(3))) void*)(l), 16, 0, 0)
#define BAR() __builtin_amdgcn_s_barrier()
#define LGKM0() asm volatile("s_waitcnt lgkmcnt(0)" ::: "memory")
#define VM4() asm volatile("s_waitcnt vmcnt(4)" ::: "memory")
#define VM2() asm volatile("s_waitcnt vmcnt(2)" ::: "memory")
#define VM0() asm volatile("s_waitcnt vmcnt(0)" ::: "memory")

__global__ __launch_bounds__(512, 2) void gemm_kernel(const unsigned short* __restrict__ A,
                                                      const unsigned short* __restrict__ Bw,
                                                      const float* __restrict__ beta_p,
                                                      float* __restrict__ C) {
  // 2 bufs x (A-tile 16384 + B-tile 16384 elems) = 128 KiB
  __shared__ __align__(16) unsigned short lds[65536];
  const int tid = threadIdx.x;
  const int lane = tid & 63;
  const int wid = tid >> 6;
  const int wr = wid >> 2;  // 0..1  (wave m-half group)
  const int wc = wid & 3;   // 0..3  (wave n group)

  // bijective XCD swizzle (512 wgs, 512%8==0)
  const int orig = blockIdx.x;
  const int wgid = (orig & 7) * 64 + (orig >> 3);
  const int m0 = (wgid >> 4) * 256;  // 32 m-tiles
  const int n0 = (wgid & 15) * 256;  // 16 n-tiles

  // --- staging addressing: linear LDS dest, inverse-swizzled global source
  // swizzle: byte_in_row ^= ((row>>2)&3)<<5  (elems: col ^= ((row>>2)&3)<<4)
  const int r8 = tid >> 3;                                      // row 0..63 in half-subtile
  const int colS = ((tid & 7) * 8) ^ (((tid >> 5) & 3) << 4);   // pre-swizzled src col
  const unsigned short* gA = A + (size_t)(m0 + r8) * KC_ + colS;
  const unsigned short* gB = Bw + (size_t)(n0 + r8) * KC_ + colS;
  unsigned short* lA = lds + tid * 8;           // + buf*32768 + half*8192 (+4096)
  unsigned short* lB = lds + 16384 + tid * 8;

  auto stageA = [&](int half, int nb, int ktn) {
    const unsigned short* gh = gA + (size_t)(half * 128) * KC_ + ktn * 64;
    unsigned short* lh = lA + nb * 32768 + half * 8192;
    GLDS16(gh, lh);
    GLDS16(gh + (size_t)64 * KC_, lh + 4096);
  };
  auto stageB = [&](int half, int nb, int ktn) {
    const unsigned short* gh = gB + (size_t)(half * 128) * KC_ + ktn * 64;
    unsigned short* lh = lB + nb * 32768 + half * 8192;
    GLDS16(gh, lh);
    GLDS16(gh + (size_t)64 * KC_, lh + 4096);
  };

  // --- ds_read addressing (swizzled): row bits2-3 == lane bits2-3
  const int swzq = ((lane >> 2) & 3) << 5;                  // byte XOR term
  const int col0 = (((lane >> 4) * 16) ^ swzq) >> 1;        // k-step 0 (elems)
  const int col1 = ((64 + (lane >> 4) * 16) ^ swzq) >> 1;   // k-step 1
  const int arow = (wr * 16 + (lane & 15)) * 64;            // A row base (elems)
  const int brow = (wc * 16 + (lane & 15)) * 64 + 16384;    // B row base

  f4v acc[8][4];
  const f4v zf = {0.f, 0.f, 0.f, 0.f};
  #pragma unroll
  for (int i = 0; i < 8; ++i)
    #pragma unroll
    for (int j = 0; j < 4; ++j)
      acc[i][j] = zf;

  // prologue: stage K-tile 0 fully into buf 0, drain
  stageA(0, 0, 0); stageA(1, 0, 0);
  stageB(0, 0, 0); stageB(1, 0, 0);
  VM0();
  BAR();

  s8v aF[4][2], bF[2][2];
  for (int kt = 0; kt < NKT; ++kt) {
    const int bo = (kt & 1) * 32768;
    const int nb = (kt & 1) ^ 1;
    const bool more = (kt + 1) < NKT;
    const int ktn = kt + 1;

    // ---- P1: quadrant (A-lo rows, B-lo cols)
    #pragma unroll
    for (int i = 0; i < 4; ++i) {
      aF[i][0] = *(const s8v*)&lds[bo + arow + i * 2048 + col0];
      aF[i][1] = *(const s8v*)&lds[bo + arow + i * 2048 + col1];
    }
    #pragma unroll
    for (int j = 0; j < 2; ++j) {
      bF[j][0] = *(const s8v*)&lds[bo + brow + j * 4096 + col0];
      bF[j][1] = *(const s8v*)&lds[bo + brow + j * 4096 + col1];
    }
    if (more) stageA(0, nb, ktn);  // A-lo(kt+1): first-used at next tile P1
    BAR();
    LGKM0();
    __builtin_amdgcn_s_setprio(1);
    #pragma unroll
    for (int i = 0; i < 4; ++i)
      #pragma unroll
      for (int j = 0; j < 2; ++j) {
        acc[i][j] = __builtin_amdgcn_mfma_f32_16x16x32_bf16(aF[i][0], bF[j][0], acc[i][j], 0, 0, 0);
        acc[i][j] = __builtin_amdgcn_mfma_f32_16x16x32_bf16(aF[i][1], bF[j][1], acc[i][j], 0, 0, 0);
      }
    __builtin_amdgcn_s_setprio(0);
    // steady state: VM4 retires B-hi(kt) (staged 3 phases ago) for P2.
    // last tile: no stages were issued this phase -> need vmcnt(2) to force
    // B-hi(31) (one of the final 4 outstanding) to land.  [round-4 bug fix]
    if (more) VM4(); else VM2();
    BAR();

    // ---- P2: quadrant (A-lo, B-hi) — A-frags reused
    #pragma unroll
    for (int j = 0; j < 2; ++j) {
      bF[j][0] = *(const s8v*)&lds[bo + brow + (2 + j) * 4096 + col0];
      bF[j][1] = *(const s8v*)&lds[bo + brow + (2 + j) * 4096 + col1];
    }
    if (more) stageB(0, nb, ktn);  // B-lo(kt+1)
    BAR();
    LGKM0();
    __builtin_amdgcn_s_setprio(1);
    #pragma unroll
    for (int i = 0; i < 4; ++i)
      #pragma unroll
      for (int j = 0; j < 2; ++j) {
        acc[i][2 + j] = __builtin_amdgcn_mfma_f32_16x16x32_bf16(aF[i][0], bF[j][0], acc[i][2 + j], 0, 0, 0);
        acc[i][2 + j] = __builtin_amdgcn_mfma_f32_16x16x32_bf16(aF[i][1], bF[j][1], acc[i][2 + j], 0, 0, 0);
      }
    __builtin_amdgcn_s_setprio(0);
    // steady: A-hi(kt) landed for P3.  last tile: drain fully (A-hi(31)).
    if (more) VM4(); else VM0();
    BAR();

    // ---- P3: quadrant (A-hi, B-hi) — B-frags reused
    #pragma unroll
    for (int i = 0; i < 4; ++i) {
      aF[i][0] = *(const s8v*)&lds[bo + arow + (4 + i) * 2048 + col0];
      aF[i][1] = *(const s8v*)&lds[bo + arow + (4 + i) * 2048 + col1];
    }
    if (more) stageB(1, nb, ktn);  // B-hi(kt+1)
    BAR();
    LGKM0();
    __builtin_amdgcn_s_setprio(1);
    #pragma unroll
    for (int i = 0; i < 4; ++i)
      #pragma unroll
      for (int j = 0; j < 2; ++j) {
        acc[4 + i][2 + j] = __builtin_amdgcn_mfma_f32_16x16x32_bf16(aF[i][0], bF[j][0], acc[4 + i][2 + j], 0, 0, 0);
        acc[4 + i][2 + j] = __builtin_amdgcn_mfma_f32_16x16x32_bf16(aF[i][1], bF[j][1], acc[4 + i][2 + j], 0, 0, 0);
      }
    __builtin_amdgcn_s_setprio(0);
    BAR();  // no vmcnt: P4 needs nothing new

    // ---- P4: quadrant (A-hi, B-lo) — re-read B-lo (long landed)
    #pragma unroll
    for (int j = 0; j < 2; ++j) {
      bF[j][0] = *(const s8v*)&lds[bo + brow + j * 4096 + col0];
      bF[j][1] = *(const s8v*)&lds[bo + brow + j * 4096 + col1];
    }
    if (more) stageA(1, nb, ktn);  // A-hi(kt+1)
    BAR();
    LGKM0();
    __builtin_amdgcn_s_setprio(1);
    #pragma unroll
    for (int i = 0; i < 4; ++i)
      #pragma unroll
      for (int j = 0; j < 2; ++j) {
        acc[4 + i][j] = __builtin_amdgcn_mfma_f32_16x16x32_bf16(aF[i][0], bF[j][0], acc[4 + i][j], 0, 0, 0);
        acc[4 + i][j] = __builtin_amdgcn_mfma_f32_16x16x32_bf16(aF[i][1], bF[j][1], acc[4 + i][j], 0, 0, 0);
      }
    __builtin_amdgcn_s_setprio(0);
    VM4();  // guarantees A-lo(kt+1), B-lo(kt+1) landed for next-tile P1
    BAR();
  }

  // epilogue
  const float beta = beta_p[0];
  const int crow = m0 + wr * 16 + (lane >> 4) * 4;
  const int ccol = n0 + wc * 16 + (lane & 15);
  #pragma unroll
  for (int i = 0; i < 8; ++i)
    #pragma unroll
    for (int j = 0; j < 4; ++j)
      #pragma unroll
      for (int v = 0; v < 4; ++v)
        C[(size_t)(crow + i * 32 + v) * D_DIM + ccol + j * 64] = beta * acc[i][j][v];
}

extern "C" void kernel_launch(void* const* d_in, const int* in_sizes, int n_in,
                              void* d_out, int out_size, void* d_ws, size_t ws_size,
                              hipStream_t stream) {
  const float* x = (const float*)d_in[0];
  const float* W = (const float*)d_in[1];
  float* out = (float*)d_out;
  char* ws = (char*)d_ws;

  int4* top_idx = (int4*)ws;
  float* col_imp = (float*)(ws + 8192);
  float2* partials = (float2*)(ws + 8192);  // aliases col_imp (dead after top4)
  float* beta_buf = (float*)(ws + 8192 + 16384);
  unsigned short* xc = (unsigned short*)(ws + 32768);
  unsigned short* wc = (unsigned short*)(ws + 32768 + (size_t)M_DIM * KC_ * 2);

  hipMemsetAsync(ws + 8192, 0, 16384, stream);

  colsum_kernel<<<dim3(16, 32), 256, 0, stream>>>(W, col_imp);
  top4_kernel<<<2, 256, 0, stream>>>(col_imp, top_idx);
  soft_kernel<<<2048, 1024, 0, stream>>>(W, top_idx, wc, partials);
  beta_kernel<<<1, 256, 0, stream>>>(partials, beta_buf);
  xcompact_kernel<<<16384, 256, 0, stream>>>(x, top_idx, xc);
  gemm_kernel<<<512, 512, 0, stream>>>(xc, wc, beta_buf, out);
}

// Round 6
// 399.912 us; speedup vs baseline: 3.1540x; 1.0432x over previous
//
#include <hip/hip_runtime.h>

#define D_DIM 4096   // out_f = in_f
#define M_DIM 8192   // B*S = 4*2048
#define NB_   512    // n_blocks = 4096/8
#define KC_   2048   // compacted K = 4 per block * 512
#define NKT   (KC_ / 64)  // 32 K-tiles of 64

typedef __attribute__((ext_vector_type(8))) short s8v;
typedef __attribute__((ext_vector_type(4))) float f4v;

static __device__ __forceinline__ unsigned short f2bf(float f) {
  union { float f; unsigned u; } c; c.f = f;
  unsigned r = c.u + 0x7fffu + ((c.u >> 16) & 1u);  // RNE
  return (unsigned short)(r >> 16);
}

// select element i (0..7) from two float4s without runtime-indexed array (rule #20)
static __device__ __forceinline__ float pick8(float4 a, float4 b, int i) {
  float lo = (i & 1) ? ((i & 2) ? a.w : a.y) : ((i & 2) ? a.z : a.x);
  float hi = (i & 1) ? ((i & 2) ? b.w : b.y) : ((i & 2) ? b.z : b.x);
  return (i & 4) ? hi : lo;
}

// ---- Kernel A1: col_imp[c] = sum_r |W[r][c]| ------------------------------
__global__ void colsum_kernel(const float* __restrict__ W, float* __restrict__ col_imp) {
  int col = blockIdx.x * 256 + threadIdx.x;
  int r0 = blockIdx.y * 128;
  float s = 0.f;
  #pragma unroll 4
  for (int r = r0; r < r0 + 128; ++r)
    s += fabsf(W[(size_t)r * D_DIM + col]);
  atomicAdd(&col_imp[col], s);  // 4096 distinct addresses: no hot-spot
}

// ---- Kernel A2: per 8-block, top-4 indices (desc value, asc index ties) ---
__global__ void top4_kernel(const float* __restrict__ col_imp, int4* __restrict__ top_idx) {
  int blk = blockIdx.x * 256 + threadIdx.x;
  if (blk >= NB_) return;
  float4 a = *(const float4*)&col_imp[blk * 8];
  float4 b = *(const float4*)&col_imp[blk * 8 + 4];
  float v[8] = {a.x, a.y, a.z, a.w, b.x, b.y, b.z, b.w};
  int used = 0;
  int sel[4];
  #pragma unroll
  for (int j = 0; j < 4; ++j) {
    float best = -1.f;
    int bi = 0;
    #pragma unroll
    for (int c = 0; c < 8; ++c) {
      bool ok = (((used >> c) & 1) == 0) && (v[c] > best);
      best = ok ? v[c] : best;
      bi = ok ? c : bi;
    }
    used |= (1 << bi);
    sel[j] = bi;
  }
  top_idx[blk] = make_int4(sel[0], sel[1], sel[2], sel[3]);
}

// ---- Kernel B: soft-threshold, write compact Wc (bf16), per-block partial -
__global__ __launch_bounds__(1024) void soft_kernel(const float* __restrict__ W,
                                                    const int4* __restrict__ top_idx,
                                                    unsigned short* __restrict__ Wc,
                                                    float2* __restrict__ partials) {
  __shared__ float rn[16], rd[16];
  int gtid = blockIdx.x * 1024 + threadIdx.x;
  int row = gtid >> 9, blk = gtid & 511;
  const float* base = W + (size_t)row * D_DIM + blk * 8;
  float4 a = *(const float4*)base;
  float4 b = *(const float4*)(base + 4);
  int4 idx = top_idx[blk];
  float r0 = pick8(a, b, idx.x), r1 = pick8(a, b, idx.y);
  float r2 = pick8(a, b, idx.z), r3 = pick8(a, b, idx.w);
  float a0 = fabsf(r0), a1 = fabsf(r1), a2 = fabsf(r2), a3 = fabsf(r3);
  float lo1 = fminf(a0, a1), hi1 = fmaxf(a0, a1);
  float lo2 = fminf(a2, a3), hi2 = fmaxf(a2, a3);
  float thr = fminf(fmaxf(lo1, lo2), fminf(hi1, hi2));  // 2nd-smallest of 4
  float s0 = copysignf(fmaxf(a0 - thr, 0.f), r0);
  float s1 = copysignf(fmaxf(a1 - thr, 0.f), r1);
  float s2 = copysignf(fmaxf(a2 - thr, 0.f), r2);
  float s3 = copysignf(fmaxf(a3 - thr, 0.f), r3);
  *(ushort4*)&Wc[(size_t)row * KC_ + blk * 4] =
      make_ushort4(f2bf(s0), f2bf(s1), f2bf(s2), f2bf(s3));
  float nm = r0 * s0 + r1 * s1 + r2 * s2 + r3 * s3;
  float dn = s0 * s0 + s1 * s1 + s2 * s2 + s3 * s3;
  #pragma unroll
  for (int off = 32; off > 0; off >>= 1) {
    nm += __shfl_down(nm, off);
    dn += __shfl_down(dn, off);
  }
  int wv = threadIdx.x >> 6;
  if ((threadIdx.x & 63) == 0) { rn[wv] = nm; rd[wv] = dn; }
  __syncthreads();
  if (threadIdx.x == 0) {
    float n = 0.f, d = 0.f;
    #pragma unroll
    for (int i = 0; i < 16; ++i) { n += rn[i]; d += rd[i]; }
    partials[blockIdx.x] = make_float2(n, d);
  }
}

// ---- Kernel X: compact x -> bf16; 2 blocks/thread, 16B store --------------
__global__ void xcompact_kernel(const float* __restrict__ x, const int4* __restrict__ top_idx,
                                unsigned short* __restrict__ xc) {
  int gtid = blockIdx.x * 256 + threadIdx.x;  // 2M threads
  int row = gtid >> 8, pair = gtid & 255;     // 256 block-pairs per row
  const float* base = x + (size_t)row * D_DIM + pair * 16;
  float4 a0 = *(const float4*)base;
  float4 b0 = *(const float4*)(base + 4);
  float4 a1 = *(const float4*)(base + 8);
  float4 b1 = *(const float4*)(base + 12);
  int4 i0 = top_idx[pair * 2];
  int4 i1 = top_idx[pair * 2 + 1];
  s8v o;
  o[0] = (short)f2bf(pick8(a0, b0, i0.x));
  o[1] = (short)f2bf(pick8(a0, b0, i0.y));
  o[2] = (short)f2bf(pick8(a0, b0, i0.z));
  o[3] = (short)f2bf(pick8(a0, b0, i0.w));
  o[4] = (short)f2bf(pick8(a1, b1, i1.x));
  o[5] = (short)f2bf(pick8(a1, b1, i1.y));
  o[6] = (short)f2bf(pick8(a1, b1, i1.z));
  o[7] = (short)f2bf(pick8(a1, b1, i1.w));
  *(s8v*)&xc[(size_t)row * KC_ + pair * 8] = o;
}

// ---- GEMM: 256x256 tile, BK=64, 8-phase counted-vmcnt pipeline (T2+T3+T4+T5)
// C[m][n] = beta * sum_k A[m][k]*Bw[n][k]
#define GLDS16(g, l)                                                          \
  __builtin_amdgcn_global_load_lds(                                           \
      (const __attribute__((address_space(1))) void*)(g),                     \
      (__attribute__((address_space(3))) void*)(l), 16, 0, 0)
#define BAR() __builtin_amdgcn_s_barrier()
#define LGKM0() asm volatile("s_waitcnt lgkmcnt(0)" ::: "memory")
#define VM4() asm volatile("s_waitcnt vmcnt(4)" ::: "memory")
#define VM2() asm volatile("s_waitcnt vmcnt(2)" ::: "memory")
#define VM0() asm volatile("s_waitcnt vmcnt(0)" ::: "memory")

__global__ __launch_bounds__(512, 2) void gemm_kernel(const unsigned short* __restrict__ A,
                                                      const unsigned short* __restrict__ Bw,
                                                      const float2* __restrict__ partials,
                                                      float* __restrict__ C) {
  // 2 bufs x (A-tile 16384 + B-tile 16384 elems) = 128 KiB
  __shared__ __align__(16) unsigned short lds[65536];
  const int tid = threadIdx.x;
  const int lane = tid & 63;
  const int wid = tid >> 6;
  const int wr = wid >> 2;  // 0..1  (wave m-half group)
  const int wc = wid & 3;   // 0..3  (wave n group)

  // bijective XCD swizzle (512 wgs, 512%8==0)
  const int orig = blockIdx.x;
  const int wgid = (orig & 7) * 64 + (orig >> 3);
  const int m0 = (wgid >> 4) * 256;  // 32 m-tiles
  const int n0 = (wgid & 15) * 256;  // 16 n-tiles

  // --- staging: linear LDS dest, inverse-swizzled global source.
  // LDS layout: LDS[row][slot16B] = global[row][slot ^ (row&7)]
  // (3-bit XOR: every 16-lane ds_read subgroup covers all 8 slots x2 ->
  //  uniform 2 accesses/bank = HW minimum.  Round-5's 2-bit version left a
  //  4-way imbalance per 16-lane phase -> 1.47e7 conflict-cycles.)
  const int r8 = tid >> 3;                                      // row 0..63
  const int colS = (((tid & 7) ^ ((tid >> 3) & 7)) << 3);       // pre-swizzled src col (elems)
  const unsigned short* gA = A + (size_t)(m0 + r8) * KC_ + colS;
  const unsigned short* gB = Bw + (size_t)(n0 + r8) * KC_ + colS;
  unsigned short* lA = lds + tid * 8;           // + buf*32768 + half*8192 (+4096)
  unsigned short* lB = lds + 16384 + tid * 8;

  auto stageA = [&](int half, int nb, int ktn) {
    const unsigned short* gh = gA + (size_t)(half * 128) * KC_ + ktn * 64;
    unsigned short* lh = lA + nb * 32768 + half * 8192;
    GLDS16(gh, lh);
    GLDS16(gh + (size_t)64 * KC_, lh + 4096);   // (row+64)&7 == row&7: same swz
  };
  auto stageB = [&](int half, int nb, int ktn) {
    const unsigned short* gh = gB + (size_t)(half * 128) * KC_ + ktn * 64;
    unsigned short* lh = lB + nb * 32768 + half * 8192;
    GLDS16(gh, lh);
    GLDS16(gh + (size_t)64 * KC_, lh + 4096);
  };

  // --- ds_read addressing (swizzled): all frag rows ≡ lane&15 (mod 8 = lane&7)
  const int swzb = (lane & 7) << 4;                          // byte XOR term
  const int col0 = ((((lane >> 4) * 16)) ^ swzb) >> 1;       // k-step 0 (elems)
  const int col1 = ((64 + (lane >> 4) * 16) ^ swzb) >> 1;    // k-step 1
  const int arow = (wr * 16 + (lane & 15)) * 64;             // A row base (elems)
  const int brow = (wc * 16 + (lane & 15)) * 64 + 16384;     // B row base

  f4v acc[8][4];
  const f4v zf = {0.f, 0.f, 0.f, 0.f};
  #pragma unroll
  for (int i = 0; i < 8; ++i)
    #pragma unroll
    for (int j = 0; j < 4; ++j)
      acc[i][j] = zf;

  // prologue: stage K-tile 0 fully into buf 0, drain
  stageA(0, 0, 0); stageA(1, 0, 0);
  stageB(0, 0, 0); stageB(1, 0, 0);
  VM0();
  BAR();

  s8v aF[4][2], bF[2][2];
  for (int kt = 0; kt < NKT; ++kt) {
    const int bo = (kt & 1) * 32768;
    const int nb = (kt & 1) ^ 1;
    const bool more = (kt + 1) < NKT;
    const int ktn = kt + 1;

    // ---- P1: quadrant (A-lo rows, B-lo cols)
    #pragma unroll
    for (int i = 0; i < 4; ++i) {
      aF[i][0] = *(const s8v*)&lds[bo + arow + i * 2048 + col0];
      aF[i][1] = *(const s8v*)&lds[bo + arow + i * 2048 + col1];
    }
    #pragma unroll
    for (int j = 0; j < 2; ++j) {
      bF[j][0] = *(const s8v*)&lds[bo + brow + j * 4096 + col0];
      bF[j][1] = *(const s8v*)&lds[bo + brow + j * 4096 + col1];
    }
    if (more) stageA(0, nb, ktn);  // A-lo(kt+1)
    BAR();
    LGKM0();
    __builtin_amdgcn_s_setprio(1);
    #pragma unroll
    for (int i = 0; i < 4; ++i)
      #pragma unroll
      for (int j = 0; j < 2; ++j) {
        acc[i][j] = __builtin_amdgcn_mfma_f32_16x16x32_bf16(aF[i][0], bF[j][0], acc[i][j], 0, 0, 0);
        acc[i][j] = __builtin_amdgcn_mfma_f32_16x16x32_bf16(aF[i][1], bF[j][1], acc[i][j], 0, 0, 0);
      }
    __builtin_amdgcn_s_setprio(0);
    // steady: VM4 retires B-hi(kt) for P2.  last tile: vmcnt(2) forces it.
    if (more) VM4(); else VM2();
    BAR();

    // ---- P2: quadrant (A-lo, B-hi) — A-frags reused
    #pragma unroll
    for (int j = 0; j < 2; ++j) {
      bF[j][0] = *(const s8v*)&lds[bo + brow + (2 + j) * 4096 + col0];
      bF[j][1] = *(const s8v*)&lds[bo + brow + (2 + j) * 4096 + col1];
    }
    if (more) stageB(0, nb, ktn);  // B-lo(kt+1)
    BAR();
    LGKM0();
    __builtin_amdgcn_s_setprio(1);
    #pragma unroll
    for (int i = 0; i < 4; ++i)
      #pragma unroll
      for (int j = 0; j < 2; ++j) {
        acc[i][2 + j] = __builtin_amdgcn_mfma_f32_16x16x32_bf16(aF[i][0], bF[j][0], acc[i][2 + j], 0, 0, 0);
        acc[i][2 + j] = __builtin_amdgcn_mfma_f32_16x16x32_bf16(aF[i][1], bF[j][1], acc[i][2 + j], 0, 0, 0);
      }
    __builtin_amdgcn_s_setprio(0);
    // steady: A-hi(kt) landed for P3.  last tile: full drain.
    if (more) VM4(); else VM0();
    BAR();

    // ---- P3: quadrant (A-hi, B-hi) — B-frags reused
    #pragma unroll
    for (int i = 0; i < 4; ++i) {
      aF[i][0] = *(const s8v*)&lds[bo + arow + (4 + i) * 2048 + col0];
      aF[i][1] = *(const s8v*)&lds[bo + arow + (4 + i) * 2048 + col1];
    }
    if (more) stageB(1, nb, ktn);  // B-hi(kt+1)
    BAR();
    LGKM0();
    __builtin_amdgcn_s_setprio(1);
    #pragma unroll
    for (int i = 0; i < 4; ++i)
      #pragma unroll
      for (int j = 0; j < 2; ++j) {
        acc[4 + i][2 + j] = __builtin_amdgcn_mfma_f32_16x16x32_bf16(aF[i][0], bF[j][0], acc[4 + i][2 + j], 0, 0, 0);
        acc[4 + i][2 + j] = __builtin_amdgcn_mfma_f32_16x16x32_bf16(aF[i][1], bF[j][1], acc[4 + i][2 + j], 0, 0, 0);
      }
    __builtin_amdgcn_s_setprio(0);
    BAR();  // no vmcnt: P4 needs nothing new

    // ---- P4: quadrant (A-hi, B-lo) — re-read B-lo (long landed)
    #pragma unroll
    for (int j = 0; j < 2; ++j) {
      bF[j][0] = *(const s8v*)&lds[bo + brow + j * 4096 + col0];
      bF[j][1] = *(const s8v*)&lds[bo + brow + j * 4096 + col1];
    }
    if (more) stageA(1, nb, ktn);  // A-hi(kt+1)
    BAR();
    LGKM0();
    __builtin_amdgcn_s_setprio(1);
    #pragma unroll
    for (int i = 0; i < 4; ++i)
      #pragma unroll
      for (int j = 0; j < 2; ++j) {
        acc[4 + i][j] = __builtin_amdgcn_mfma_f32_16x16x32_bf16(aF[i][0], bF[j][0], acc[4 + i][j], 0, 0, 0);
        acc[4 + i][j] = __builtin_amdgcn_mfma_f32_16x16x32_bf16(aF[i][1], bF[j][1], acc[4 + i][j], 0, 0, 0);
      }
    __builtin_amdgcn_s_setprio(0);
    VM4();  // A-lo(kt+1), B-lo(kt+1) landed for next-tile P1
    BAR();
  }

  // ---- beta: redundant per-block reduction of 2048 partials (deterministic)
  float nm = 0.f, dn = 0.f;
  #pragma unroll
  for (int i = 0; i < 4; ++i) {
    float2 p = partials[tid + i * 512];
    nm += p.x; dn += p.y;
  }
  #pragma unroll
  for (int off = 32; off > 0; off >>= 1) {
    nm += __shfl_down(nm, off);
    dn += __shfl_down(dn, off);
  }
  float* lsc = (float*)lds;
  __syncthreads();  // K-loop LDS fully consumed
  if (lane == 0) { lsc[wid * 2] = nm; lsc[wid * 2 + 1] = dn; }
  __syncthreads();
  float n = 0.f, d = 0.f;
  #pragma unroll
  for (int i = 0; i < 8; ++i) { n += lsc[i * 2]; d += lsc[i * 2 + 1]; }
  const float beta = (d > 0.f) ? (n / d) : 1.f;

  // epilogue
  const int crow = m0 + wr * 16 + (lane >> 4) * 4;
  const int ccol = n0 + wc * 16 + (lane & 15);
  #pragma unroll
  for (int i = 0; i < 8; ++i)
    #pragma unroll
    for (int j = 0; j < 4; ++j)
      #pragma unroll
      for (int v = 0; v < 4; ++v)
        C[(size_t)(crow + i * 32 + v) * D_DIM + ccol + j * 64] = beta * acc[i][j][v];
}

extern "C" void kernel_launch(void* const* d_in, const int* in_sizes, int n_in,
                              void* d_out, int out_size, void* d_ws, size_t ws_size,
                              hipStream_t stream) {
  const float* x = (const float*)d_in[0];
  const float* W = (const float*)d_in[1];
  float* out = (float*)d_out;
  char* ws = (char*)d_ws;

  int4* top_idx = (int4*)ws;
  float* col_imp = (float*)(ws + 8192);
  float2* partials = (float2*)(ws + 8192);  // aliases col_imp (dead after top4)
  unsigned short* xc = (unsigned short*)(ws + 32768);
  unsigned short* wc = (unsigned short*)(ws + 32768 + (size_t)M_DIM * KC_ * 2);

  hipMemsetAsync(ws + 8192, 0, 16384, stream);

  colsum_kernel<<<dim3(16, 32), 256, 0, stream>>>(W, col_imp);
  top4_kernel<<<2, 256, 0, stream>>>(col_imp, top_idx);
  soft_kernel<<<2048, 1024, 0, stream>>>(W, top_idx, wc, partials);
  xcompact_kernel<<<8192, 256, 0, stream>>>(x, top_idx, xc);
  gemm_kernel<<<512, 512, 0, stream>>>(xc, wc, partials, out);
}